// Round 2
// baseline (167.933 us; speedup 1.0000x reference)
//
#include <hip/hip_runtime.h>
#include <hip/hip_bf16.h>

// Problem constants
constexpr int Dd = 1024;           // feature dim
constexpr int Tt = 2048;           // sequence length
constexpr int Bb = 4;              // batch
constexpr int Rr = Bb * Tt;        // GEMM rows = 8192
constexpr int NCHUNK = 32;         // scan chunks
constexpr int CLEN = Tt / NCHUNK;  // 64 steps per chunk
constexpr int JROWS = Bb * NCHUNK; // 128 carry rows

typedef __attribute__((ext_vector_type(4))) float f32x4;
typedef __attribute__((ext_vector_type(8))) short bf16x8;

__device__ __forceinline__ float sigmoidf_(float v) {
    return 1.0f / (1.0f + expf(-v));
}

__device__ __forceinline__ void async16(const void* g, void* l) {
    __builtin_amdgcn_global_load_lds(
        (const __attribute__((address_space(1))) unsigned int*)g,
        (__attribute__((address_space(3))) unsigned int*)l,
        16, 0, 0);
}

// ---------------------------------------------------------------------------
// Kernel 1: combined circulant kernel c[n] = sum_m unbind[m] * bind[(m+n)%D]
// grid 4 x 256
__global__ void k_combine(const float* __restrict__ bind,
                          const float* __restrict__ unbind,
                          float* __restrict__ c) {
    __shared__ float sb[Dd];
    __shared__ float su[Dd];
    int t = threadIdx.x;
    for (int j = t; j < Dd; j += 256) { sb[j] = bind[j]; su[j] = unbind[j]; }
    __syncthreads();
    int n = blockIdx.x * 256 + t;
    float acc = 0.f;
    #pragma unroll 8
    for (int m = 0; m < Dd; ++m) acc = fmaf(su[m], sb[(m + n) & (Dd - 1)], acc);
    c[n] = acc;
}

// ---------------------------------------------------------------------------
// Kernel 2: Wt[n][k] = bf16(c[(n-k) mod D]); vectorized 8 elems / thread
// grid 512 x 256
__global__ void k_build_w(const float* __restrict__ c,
                          __hip_bfloat16* __restrict__ wt) {
    int idx8 = blockIdx.x * 256 + threadIdx.x;  // 131072 groups of 8
    int n = idx8 >> 7;
    int k0 = (idx8 & 127) * 8;
    bf16x8 v;
    #pragma unroll
    for (int j = 0; j < 8; ++j) {
        union { __hip_bfloat16 b; short s; } u;
        u.b = __float2bfloat16(c[(n - (k0 + j)) & (Dd - 1)]);
        v[j] = u.s;
    }
    *(bf16x8*)&wt[(size_t)n * Dd + k0] = v;
}

// ---------------------------------------------------------------------------
// Kernel 3: local (carry-free) EMA scan; write bf16 xs + fp32 endvals.
// grid 512 x 256  (one thread per (b,chunk,i) column)
__global__ void k_scan_local(const float* __restrict__ x,
                             const float* __restrict__ decay,
                             __hip_bfloat16* __restrict__ xs,
                             float* __restrict__ endv) {
    int idx = blockIdx.x * 256 + threadIdx.x;
    int i = idx & (Dd - 1);
    int chunk = (idx >> 10) & (NCHUNK - 1);
    int b = idx >> 15;
    float dd = sigmoidf_(decay[0]);
    size_t base = ((size_t)b * Tt + (size_t)chunk * CLEN) * Dd + i;
    float h = 0.f;
    #pragma unroll 8
    for (int t = 0; t < CLEN; ++t) {
        h = fmaf(dd, h, x[base + (size_t)t * Dd]);
        xs[base + (size_t)t * Dd] = __float2bfloat16(h);
    }
    endv[idx] = h;
}

// ---------------------------------------------------------------------------
// Kernel 4: cross-chunk carries -> bf16 rows [b*32+c][i]
// grid 16 x 256 (B*D threads)
__global__ void k_carries(const float* __restrict__ endv,
                          const float* __restrict__ decay,
                          __hip_bfloat16* __restrict__ carry) {
    int idx = blockIdx.x * 256 + threadIdx.x;
    int i = idx & (Dd - 1);
    int b = idx >> 10;
    float dd = sigmoidf_(decay[0]);
    float dL = powf(dd, (float)CLEN);
    float run = 0.f;
    #pragma unroll
    for (int c = 0; c < NCHUNK; ++c) {
        size_t off = ((size_t)b * NCHUNK + c) * Dd + i;
        carry[off] = __float2bfloat16(run);
        run = fmaf(dL, run, endv[off]);
    }
}

// ---------------------------------------------------------------------------
// GEMM: 128x128 tile, BK=32, 4 waves 2x2, 16x16x32 bf16 MFMA, async staging.
// MAIN=true : out[r][n] = x[r][n] + g*(acc + d^{(r&63)+1} * corrW[r>>6][n])
// MAIN=false: out[row][col] = acc   (used for corrW = carry @ W)
template <bool MAIN>
__global__ __launch_bounds__(256) void k_gemm_t(
    const __hip_bfloat16* __restrict__ A,   // [rows][D] bf16
    const __hip_bfloat16* __restrict__ Wt,  // [D][D] bf16, Wt[n][k]
    const float* __restrict__ x,            // [R][D] fp32 (MAIN only)
    const float* __restrict__ gate,         // [1]      (MAIN only)
    const float* __restrict__ decay,        // [1]      (MAIN only)
    const float* __restrict__ corrW,        // [128][D] (MAIN only)
    float* __restrict__ out)
{
    __shared__ __align__(16) __hip_bfloat16 sA[128 * 32];
    __shared__ __align__(16) __hip_bfloat16 sB[128 * 32];

    const int tid = threadIdx.x;
    const int wave = tid >> 6;
    const int lane = tid & 63;
    const int tile_m = blockIdx.x * 128;
    const int tile_n = blockIdx.y * 128;
    const int wm = (wave & 1) * 64;
    const int wn = (wave >> 1) * 64;

    f32x4 acc[4][4];
    #pragma unroll
    for (int i = 0; i < 4; ++i)
        #pragma unroll
        for (int j = 0; j < 4; ++j)
            acc[i][j] = (f32x4){0.f, 0.f, 0.f, 0.f};

    const int srow = lane >> 2;
    const int skk  = (lane & 3) * 8;
    const int fr = lane & 15;
    const int fk = (lane >> 4) * 8;

    for (int k0 = 0; k0 < Dd; k0 += 32) {
        __syncthreads();
        #pragma unroll
        for (int j = 0; j < 2; ++j) {
            const int row = wave * 32 + j * 16;  // wave-uniform
            async16(A  + (size_t)(tile_m + row + srow) * Dd + k0 + skk, &sA[row * 32]);
            async16(Wt + (size_t)(tile_n + row + srow) * Dd + k0 + skk, &sB[row * 32]);
        }
        __syncthreads();

        bf16x8 af[4], bfr[4];
        #pragma unroll
        for (int mt = 0; mt < 4; ++mt)
            af[mt] = *(const bf16x8*)&sA[(wm + mt * 16 + fr) * 32 + fk];
        #pragma unroll
        for (int nt = 0; nt < 4; ++nt)
            bfr[nt] = *(const bf16x8*)&sB[(wn + nt * 16 + fr) * 32 + fk];

        #pragma unroll
        for (int mt = 0; mt < 4; ++mt)
            #pragma unroll
            for (int nt = 0; nt < 4; ++nt)
                acc[mt][nt] = __builtin_amdgcn_mfma_f32_16x16x32_bf16(
                    af[mt], bfr[nt], acc[mt][nt], 0, 0, 0);
    }

    if (MAIN) {
        const float g = gate[0];
        const float dd = sigmoidf_(decay[0]);
        const float l2d = log2f(dd);
        #pragma unroll
        for (int mt = 0; mt < 4; ++mt) {
            const int row0 = tile_m + wm + mt * 16 + (lane >> 4) * 4;
            const int j = row0 >> 6;  // carry-row index (4-row group never crosses 64)
            float scale[4];
            #pragma unroll
            for (int gg = 0; gg < 4; ++gg)
                scale[gg] = exp2f((float)(((row0 + gg) & 63) + 1) * l2d);
            #pragma unroll
            for (int nt = 0; nt < 4; ++nt) {
                const int col = tile_n + wn + nt * 16 + (lane & 15);
                const float cw = corrW[(size_t)j * Dd + col];
                #pragma unroll
                for (int gg = 0; gg < 4; ++gg) {
                    const size_t off = (size_t)(row0 + gg) * Dd + col;
                    out[off] = fmaf(g, fmaf(scale[gg], cw, acc[mt][nt][gg]), x[off]);
                }
            }
        }
    } else {
        #pragma unroll
        for (int mt = 0; mt < 4; ++mt) {
            const int row0 = tile_m + wm + mt * 16 + (lane >> 4) * 4;
            #pragma unroll
            for (int nt = 0; nt < 4; ++nt) {
                const int col = tile_n + wn + nt * 16 + (lane & 15);
                #pragma unroll
                for (int gg = 0; gg < 4; ++gg)
                    out[(size_t)(row0 + gg) * Dd + col] = acc[mt][nt][gg];
            }
        }
    }
}

// ---------------------------------------------------------------------------
extern "C" void kernel_launch(void* const* d_in, const int* in_sizes, int n_in,
                              void* d_out, int out_size, void* d_ws, size_t ws_size,
                              hipStream_t stream) {
    const float* x      = (const float*)d_in[0];
    const float* bind   = (const float*)d_in[1];
    const float* unbind = (const float*)d_in[2];
    const float* gate   = (const float*)d_in[3];
    const float* decay  = (const float*)d_in[4];
    float* out = (float*)d_out;

    // workspace layout (~18.8 MB; corrW aliases endv, which is dead by then)
    char* ws = (char*)d_ws;
    float* c = (float*)ws;                                                  // 4 KB
    __hip_bfloat16* wt = (__hip_bfloat16*)(ws + 4096);                      // 2 MB
    __hip_bfloat16* xs = (__hip_bfloat16*)(ws + 4096 + (size_t)Dd*Dd*2);    // 16 MB
    char* p3 = ws + 4096 + (size_t)Dd*Dd*2 + (size_t)Rr*Dd*2;
    float* endv = (float*)p3;                                               // 512 KB
    float* corrW = endv;                                                    // alias (endv dead after k_carries)
    __hip_bfloat16* carry = (__hip_bfloat16*)(p3 + (size_t)Bb*NCHUNK*Dd*4); // 256 KB

    k_combine   <<<dim3(4),      dim3(256), 0, stream>>>(bind, unbind, c);
    k_build_w   <<<dim3(512),    dim3(256), 0, stream>>>(c, wt);
    k_scan_local<<<dim3(512),    dim3(256), 0, stream>>>(x, decay, xs, endv);
    k_carries   <<<dim3(16),     dim3(256), 0, stream>>>(endv, decay, carry);
    // corrW = carry @ W : 128x1024x1024, grid (1,8)
    k_gemm_t<false><<<dim3(1, 8),  dim3(256), 0, stream>>>(carry, wt, nullptr, nullptr, nullptr, nullptr, corrW);
    // main GEMM + epilogue
    k_gemm_t<true> <<<dim3(64, 8), dim3(256), 0, stream>>>(xs, wt, x, gate, decay, corrW, out);
}